// Round 1
// baseline (675.918 us; speedup 1.0000x reference)
//
#include <hip/hip_runtime.h>
#include <hip/hip_bf16.h>

typedef __bf16 bf16x8 __attribute__((ext_vector_type(8)));
typedef float f32x4 __attribute__((ext_vector_type(4)));

#define LR_SLOPE 0.2f

static __device__ __forceinline__ unsigned short f2bf(float f){
  union { float f; unsigned u; } v; v.f = f;
  unsigned u = v.u;
  u += 0x7fffu + ((u >> 16) & 1u);   // round-to-nearest-even
  return (unsigned short)(u >> 16);
}
static __device__ __forceinline__ unsigned pk2(float a, float b){
  return (unsigned)f2bf(a) | ((unsigned)f2bf(b) << 16);
}

// ---------------- weight prep: transpose + bf16 ----------------
__global__ void prep_w1_kernel(const float* __restrict__ W1, unsigned short* __restrict__ wt1){
  int t = blockIdx.x*256 + threadIdx.x;
  if (t >= 512*64) return;
  int k = t >> 6, n = t & 63;            // W1[k][n], row-major read coalesced
  wt1[n*512 + k] = f2bf(W1[t]);          // wt1[n][k]
}

__global__ void prep_w2_kernel(const float* __restrict__ W2, unsigned short* __restrict__ wt2){
  int t = blockIdx.x*256 + threadIdx.x;
  if (t >= 48*64) return;
  int c = t >> 6, k = t & 63;            // wt2[c][k], cols 40..47 zero-padded
  wt2[t] = (c < 40) ? f2bf(W2[k*40 + c]) : (unsigned short)0;
}

// ---------------- GEMM1: h1[N,64] = x[N,512] @ W1 (bf16 MFMA) ----------------
__global__ __launch_bounds__(256) void gemm1_kernel(
    const float* __restrict__ x, const unsigned short* __restrict__ wt1,
    float* __restrict__ h1, int N)
{
  __shared__ unsigned short Alds[64*72];          // 64 rows x 64 k, pitch 72 (16B aligned)
  const int tid = threadIdx.x;
  const int wv = tid >> 6, lane = tid & 63;
  const int c0 = lane & 15, g = lane >> 4;
  const int rowbase = blockIdx.x * 64;

  const int sr = tid >> 2, sq = tid & 3;          // staging: row, 16-float chunk
  const int grow = rowbase + sr;
  const bool rv = grow < N;
  const float* xp = x + (size_t)grow*512 + sq*16;
  unsigned short* wls = Alds + sr*72 + sq*16;

  f32x4 acc[4];
  acc[0] = acc[1] = acc[2] = acc[3] = (f32x4){0.f,0.f,0.f,0.f};

  const unsigned short* bp0 = wt1 + (size_t)(wv*16 + c0)*512 + g*8;

  for (int kt = 0; kt < 8; ++kt){
    float4 f0 = {0,0,0,0}, f1 = {0,0,0,0}, f2 = {0,0,0,0}, f3 = {0,0,0,0};
    if (rv){
      const float4* p = (const float4*)(xp + kt*64);
      f0 = p[0]; f1 = p[1]; f2 = p[2]; f3 = p[3];
    }
    uint4 w0 = { pk2(f0.x,f0.y), pk2(f0.z,f0.w), pk2(f1.x,f1.y), pk2(f1.z,f1.w) };
    uint4 w1 = { pk2(f2.x,f2.y), pk2(f2.z,f2.w), pk2(f3.x,f3.y), pk2(f3.z,f3.w) };
    if (kt) __syncthreads();                      // previous tile fully consumed
    *(uint4*)wls       = w0;
    *(uint4*)(wls + 8) = w1;
    __syncthreads();
    bf16x8 b0 = *(const bf16x8*)(bp0 + kt*64);
    bf16x8 b1 = *(const bf16x8*)(bp0 + kt*64 + 32);
    #pragma unroll
    for (int mi = 0; mi < 4; ++mi){
      const unsigned short* ap = Alds + (mi*16 + c0)*72 + g*8;
      bf16x8 a0 = *(const bf16x8*)ap;
      bf16x8 a1 = *(const bf16x8*)(ap + 32);
      acc[mi] = __builtin_amdgcn_mfma_f32_16x16x32_bf16(a0, b0, acc[mi], 0,0,0);
      acc[mi] = __builtin_amdgcn_mfma_f32_16x16x32_bf16(a1, b1, acc[mi], 0,0,0);
    }
  }
  #pragma unroll
  for (int mi = 0; mi < 4; ++mi){
    #pragma unroll
    for (int i = 0; i < 4; ++i){
      int row = rowbase + mi*16 + 4*g + i;        // D: row=(lane>>4)*4+reg, col=lane&15
      if (row < N) h1[(size_t)row*64 + wv*16 + c0] = acc[mi][i];
    }
  }
}

// ---------------- attn1: per (node,head) dot with att vectors ----------------
__global__ void attn1_kernel(const float* __restrict__ h1,
    const float* __restrict__ aw_s, const float* __restrict__ aw_d,
    float* __restrict__ as1, float* __restrict__ ad1, int N)
{
  int t = blockIdx.x*256 + threadIdx.x;
  if (t >= N*8) return;
  int h = t & 7;
  const float* hp = h1 + (size_t)t*8;             // n*64 + h*8 == t*8
  float4 a = *(const float4*)hp;
  float4 b = *(const float4*)(hp + 4);
  const float* ws = aw_s + h*8;
  const float* wd = aw_d + h*8;
  float s = a.x*ws[0]+a.y*ws[1]+a.z*ws[2]+a.w*ws[3]+b.x*ws[4]+b.y*ws[5]+b.z*ws[6]+b.w*ws[7];
  float d = a.x*wd[0]+a.y*wd[1]+a.z*wd[2]+a.w*wd[3]+b.x*wd[4]+b.y*wd[5]+b.z*wd[6]+b.w*wd[7];
  as1[t] = s; ad1[t] = d;
}

// ---------------- CSR build ----------------
__global__ void init_deg_kernel(int* __restrict__ deg, int N){
  int t = blockIdx.x*256 + threadIdx.x;
  if (t < N) deg[t] = 1;                          // self-loop pre-counted
}

__global__ void hist_kernel(const int* __restrict__ ei, int* __restrict__ deg, int E){
  int t = blockIdx.x*256 + threadIdx.x;
  if (t < E) atomicAdd(&deg[ei[E + t]], 1);       // row 1 = dst
}

__global__ void scan1_kernel(const int* __restrict__ deg, int* __restrict__ rowstart,
                             int* __restrict__ partial, int N){
  __shared__ int sc[256];
  int t = threadIdx.x;
  int base = blockIdx.x*1024 + t*4;
  int d0=0,d1=0,d2=0,d3=0;
  if (base + 3 < N){
    int4 v = *(const int4*)(deg + base);
    d0=v.x; d1=v.y; d2=v.z; d3=v.w;
  } else {
    if (base   < N) d0 = deg[base];
    if (base+1 < N) d1 = deg[base+1];
    if (base+2 < N) d2 = deg[base+2];
    if (base+3 < N) d3 = deg[base+3];
  }
  int s = d0+d1+d2+d3;
  sc[t] = s; __syncthreads();
  for (int off = 1; off < 256; off <<= 1){
    int v = (t >= off) ? sc[t-off] : 0;
    __syncthreads();
    if (t >= off) sc[t] += v;
    __syncthreads();
  }
  int excl = sc[t] - s;
  if (base   < N) rowstart[base]   = excl;
  if (base+1 < N) rowstart[base+1] = excl + d0;
  if (base+2 < N) rowstart[base+2] = excl + d0 + d1;
  if (base+3 < N) rowstart[base+3] = excl + d0 + d1 + d2;
  if (t == 255) partial[blockIdx.x] = sc[255];
}

__global__ void scan2_kernel(int* __restrict__ partial, int NB){
  __shared__ int sc[128];
  int t = threadIdx.x;
  int v = (t < NB) ? partial[t] : 0;
  sc[t] = v; __syncthreads();
  for (int off = 1; off < 128; off <<= 1){
    int u = (t >= off) ? sc[t-off] : 0;
    __syncthreads();
    if (t >= off) sc[t] += u;
    __syncthreads();
  }
  if (t < NB) partial[t] = sc[t] - v;
  if (t == 127) partial[NB] = sc[127];            // grand total = E + N
}

__global__ void scan3_kernel(int* __restrict__ rowstart, int* __restrict__ cursor,
                             const int* __restrict__ partial, int N, int NB){
  int t = blockIdx.x*256 + threadIdx.x;
  if (t < N){
    int v = rowstart[t] + partial[t >> 10];
    rowstart[t] = v;
    cursor[t]  = v;
  }
  if (t == 0) rowstart[N] = partial[NB];
}

__global__ void scatter_kernel(const int* __restrict__ ei, int* __restrict__ cursor,
                               int* __restrict__ csr, int E, int M){
  int t = blockIdx.x*256 + threadIdx.x;
  if (t >= M) return;
  int s, d;
  if (t < E){ s = ei[t]; d = ei[E + t]; }
  else      { s = d = t - E; }                    // self loops
  int pos = atomicAdd(&cursor[d], 1);
  csr[pos] = s;
}

// ---------------- layer-1 aggregation: wave per dst, 64 features ----------------
__global__ void l1agg_kernel(const int* __restrict__ rowstart, const int* __restrict__ csr,
    const float* __restrict__ as1, const float* __restrict__ ad1,
    const float* __restrict__ h1, const float* __restrict__ b1,
    float* __restrict__ g1, int N)
{
  int wid = blockIdx.x*4 + (threadIdx.x >> 6);
  if (wid >= N) return;
  int lane = threadIdx.x & 63;
  int h = lane >> 3;
  int r0 = rowstart[wid], r1 = rowstart[wid+1];
  float adv = ad1[wid*8 + h];
  float acc = 0.f, den = 0.f;
  for (int r = r0; r < r1; ++r){
    int s = csr[r];
    float e = as1[s*8 + h] + adv;
    e = (e > 0.f) ? e : LR_SLOPE*e;
    float w = __expf(e);
    den += w;
    acc = fmaf(w, h1[(size_t)s*64 + lane], acc);
  }
  float v = acc/den + b1[lane];
  g1[(size_t)wid*64 + lane] = (v > 0.f) ? v : (__expf(v) - 1.f);   // ELU fused
}

// ---------------- GEMM2: h2[N,40] = g1[N,64] @ W2 (bf16 MFMA, 48-col pad) ----------------
__global__ __launch_bounds__(256) void gemm2_kernel(
    const float* __restrict__ g1, const unsigned short* __restrict__ wt2,
    float* __restrict__ h2, int N)
{
  __shared__ unsigned short Alds[64*72];
  const int tid = threadIdx.x;
  const int wv = tid >> 6, lane = tid & 63;
  const int c0 = lane & 15, g = lane >> 4;
  const int rowbase = blockIdx.x * 64;

  const int sr = tid >> 2, sq = tid & 3;
  const int grow = rowbase + sr;
  const bool rv = grow < N;
  float4 f0 = {0,0,0,0}, f1 = {0,0,0,0}, f2 = {0,0,0,0}, f3 = {0,0,0,0};
  if (rv){
    const float4* p = (const float4*)(g1 + (size_t)grow*64 + sq*16);
    f0 = p[0]; f1 = p[1]; f2 = p[2]; f3 = p[3];
  }
  uint4 w0 = { pk2(f0.x,f0.y), pk2(f0.z,f0.w), pk2(f1.x,f1.y), pk2(f1.z,f1.w) };
  uint4 w1 = { pk2(f2.x,f2.y), pk2(f2.z,f2.w), pk2(f3.x,f3.y), pk2(f3.z,f3.w) };
  unsigned short* wls = Alds + sr*72 + sq*16;
  *(uint4*)wls       = w0;
  *(uint4*)(wls + 8) = w1;
  __syncthreads();

  f32x4 acc[3];
  acc[0] = acc[1] = acc[2] = (f32x4){0.f,0.f,0.f,0.f};
  #pragma unroll
  for (int t2 = 0; t2 < 2; ++t2){
    const unsigned short* ap = Alds + (wv*16 + c0)*72 + t2*32 + g*8;
    bf16x8 a = *(const bf16x8*)ap;
    #pragma unroll
    for (int nf = 0; nf < 3; ++nf){
      bf16x8 b = *(const bf16x8*)(wt2 + (nf*16 + c0)*64 + t2*32 + g*8);
      acc[nf] = __builtin_amdgcn_mfma_f32_16x16x32_bf16(a, b, acc[nf], 0,0,0);
    }
  }
  #pragma unroll
  for (int nf = 0; nf < 3; ++nf){
    int col = nf*16 + c0;
    #pragma unroll
    for (int i = 0; i < 4; ++i){
      int row = rowbase + wv*16 + 4*g + i;
      if (row < N && col < 40) h2[(size_t)row*40 + col] = acc[nf][i];
    }
  }
}

// ---------------- attn2: 8 lanes per node, 5 features each ----------------
__global__ void attn2_kernel(const float* __restrict__ h2,
    const float* __restrict__ aw_s, const float* __restrict__ aw_d,
    float* __restrict__ as2, float* __restrict__ ad2, int N)
{
  int tid = threadIdx.x;
  int wv = blockIdx.x*4 + (tid >> 6);
  int lane = tid & 63;
  int n = wv*8 + (lane >> 3);
  int cq = (lane & 7)*5;
  float s = 0.f, d = 0.f;
  if (n < N){
    const float* hp = h2 + (size_t)n*40 + cq;
    #pragma unroll
    for (int j = 0; j < 5; ++j){
      float hv = hp[j];
      s += hv * aw_s[cq + j];
      d += hv * aw_d[cq + j];
    }
  }
  s += __shfl_xor(s, 1); s += __shfl_xor(s, 2); s += __shfl_xor(s, 4);
  d += __shfl_xor(d, 1); d += __shfl_xor(d, 2); d += __shfl_xor(d, 4);
  if (n < N && (lane & 7) == 0){ as2[n] = s; ad2[n] = d; }
}

// ---------------- layer-2 aggregation + bias + log_softmax ----------------
__global__ void l2agg_kernel(const int* __restrict__ rowstart, const int* __restrict__ csr,
    const float* __restrict__ as2, const float* __restrict__ ad2,
    const float* __restrict__ h2, const float* __restrict__ b2,
    float* __restrict__ out, int N)
{
  int wid = blockIdx.x*4 + (threadIdx.x >> 6);
  if (wid >= N) return;
  int lane = threadIdx.x & 63;
  bool act = lane < 40;
  int r0 = rowstart[wid], r1 = rowstart[wid+1];
  float adv = ad2[wid];
  float acc = 0.f, den = 0.f;
  for (int r = r0; r < r1; ++r){
    int s = csr[r];
    float e = as2[s] + adv;
    e = (e > 0.f) ? e : LR_SLOPE*e;
    float w = __expf(e);
    den += w;
    if (act) acc = fmaf(w, h2[(size_t)s*40 + lane], acc);
  }
  float v = act ? (acc/den + b2[lane]) : -1e30f;
  float m = v;
  #pragma unroll
  for (int off = 32; off; off >>= 1) m = fmaxf(m, __shfl_xor(m, off));
  float ex = act ? __expf(v - m) : 0.f;
  float sum = ex;
  #pragma unroll
  for (int off = 32; off; off >>= 1) sum += __shfl_xor(sum, off);
  if (act) out[(size_t)wid*40 + lane] = v - m - __logf(sum);
}

// ---------------- host ----------------
extern "C" void kernel_launch(void* const* d_in, const int* in_sizes, int n_in,
                              void* d_out, int out_size, void* d_ws, size_t ws_size,
                              hipStream_t stream)
{
  const float* x   = (const float*)d_in[0];
  const int*   ei  = (const int*)d_in[1];
  const float* W1  = (const float*)d_in[2];
  const float* aS1 = (const float*)d_in[3];
  const float* aD1 = (const float*)d_in[4];
  const float* b1  = (const float*)d_in[5];
  const float* W2  = (const float*)d_in[6];
  const float* aS2 = (const float*)d_in[7];
  const float* aD2 = (const float*)d_in[8];
  const float* b2  = (const float*)d_in[9];

  const int N  = in_sizes[0] / 512;
  const int E  = in_sizes[1] / 2;
  const int M  = E + N;
  const int NB = (N + 1023) >> 10;

  char* base = (char*)d_ws;
  size_t off = 0;
  auto alloc = [&](size_t bytes)->char* {
    char* p = base + off;
    off += (bytes + 255) & ~(size_t)255;
    return p;
  };
  float* h1       = (float*)alloc((size_t)N*64*4);
  float* g1       = (float*)alloc((size_t)N*64*4);
  float* as1      = (float*)alloc((size_t)N*8*4);
  float* ad1      = (float*)alloc((size_t)N*8*4);
  int*   deg      = (int*)alloc((size_t)N*4);
  int*   rowstart = (int*)alloc((size_t)(N+1)*4);
  int*   cursor   = (int*)alloc((size_t)N*4);
  int*   csr      = (int*)alloc((size_t)M*4);
  int*   partial  = (int*)alloc(1024);
  unsigned short* wt1 = (unsigned short*)alloc(64*512*2);
  unsigned short* wt2 = (unsigned short*)alloc(48*64*2);
  // safe aliases (h1/as1/ad1 dead after l1agg)
  float* h2  = h1;
  float* as2 = as1;
  float* ad2 = ad1;
  float* outp = (float*)d_out;

  prep_w1_kernel<<<128, 256, 0, stream>>>(W1, wt1);
  prep_w2_kernel<<<12, 256, 0, stream>>>(W2, wt2);
  gemm1_kernel<<<(N+63)/64, 256, 0, stream>>>(x, wt1, h1, N);
  attn1_kernel<<<(N*8+255)/256, 256, 0, stream>>>(h1, aS1, aD1, as1, ad1, N);
  init_deg_kernel<<<(N+255)/256, 256, 0, stream>>>(deg, N);
  hist_kernel<<<(E+255)/256, 256, 0, stream>>>(ei, deg, E);
  scan1_kernel<<<NB, 256, 0, stream>>>(deg, rowstart, partial, N);
  scan2_kernel<<<1, 128, 0, stream>>>(partial, NB);
  scan3_kernel<<<(N+255)/256, 256, 0, stream>>>(rowstart, cursor, partial, N, NB);
  scatter_kernel<<<(M+255)/256, 256, 0, stream>>>(ei, cursor, csr, E, M);
  l1agg_kernel<<<(N+3)/4, 256, 0, stream>>>(rowstart, csr, as1, ad1, h1, b1, g1, N);
  gemm2_kernel<<<(N+63)/64, 256, 0, stream>>>(g1, wt2, h2, N);
  attn2_kernel<<<(N*8+255)/256, 256, 0, stream>>>(h2, aS2, aD2, as2, ad2, N);
  l2agg_kernel<<<(N+3)/4, 256, 0, stream>>>(rowstart, csr, as2, ad2, h2, b2, outp, N);
}

// Round 2
// 454.293 us; speedup vs baseline: 1.4878x; 1.4878x over previous
//
#include <hip/hip_runtime.h>
#include <hip/hip_bf16.h>

typedef __bf16 bf16x8 __attribute__((ext_vector_type(8)));
typedef float f32x4 __attribute__((ext_vector_type(4)));

#define LR_SLOPE 0.2f
#define AGG_UNROLL 8

static __device__ __forceinline__ unsigned short f2bf(float f){
  union { float f; unsigned u; } v; v.f = f;
  unsigned u = v.u;
  u += 0x7fffu + ((u >> 16) & 1u);   // round-to-nearest-even
  return (unsigned short)(u >> 16);
}
static __device__ __forceinline__ float bf2f(unsigned short us){
  union { unsigned u; float f; } v; v.u = ((unsigned)us) << 16;
  return v.f;
}
static __device__ __forceinline__ unsigned pk2(float a, float b){
  return (unsigned)f2bf(a) | ((unsigned)f2bf(b) << 16);
}

// ---------------- weight prep: transpose + bf16 ----------------
__global__ void prep_w1_kernel(const float* __restrict__ W1, unsigned short* __restrict__ wt1){
  int t = blockIdx.x*256 + threadIdx.x;
  if (t >= 512*64) return;
  int k = t >> 6, n = t & 63;            // W1[k][n], row-major read coalesced
  wt1[n*512 + k] = f2bf(W1[t]);          // wt1[n][k]
}

__global__ void prep_w2_kernel(const float* __restrict__ W2, unsigned short* __restrict__ wt2){
  int t = blockIdx.x*256 + threadIdx.x;
  if (t >= 48*64) return;
  int c = t >> 6, k = t & 63;            // wt2[c][k], cols 40..47 zero-padded
  wt2[t] = (c < 40) ? f2bf(W2[k*40 + c]) : (unsigned short)0;
}

// ---------------- GEMM1: h1[N,64] = x[N,512] @ W1 (bf16 MFMA, bf16 out) ----------------
__global__ __launch_bounds__(256) void gemm1_kernel(
    const float* __restrict__ x, const unsigned short* __restrict__ wt1,
    unsigned short* __restrict__ h1b, int N)
{
  __shared__ unsigned short Alds[64*72];          // 64 rows x 64 k, pitch 72 (16B aligned)
  const int tid = threadIdx.x;
  const int wv = tid >> 6, lane = tid & 63;
  const int c0 = lane & 15, g = lane >> 4;
  const int rowbase = blockIdx.x * 64;

  const int sr = tid >> 2, sq = tid & 3;          // staging: row, 16-float chunk
  const int grow = rowbase + sr;
  const bool rv = grow < N;
  const float* xp = x + (size_t)grow*512 + sq*16;
  unsigned short* wls = Alds + sr*72 + sq*16;

  f32x4 acc[4];
  acc[0] = acc[1] = acc[2] = acc[3] = (f32x4){0.f,0.f,0.f,0.f};

  const unsigned short* bp0 = wt1 + (size_t)(wv*16 + c0)*512 + g*8;

  for (int kt = 0; kt < 8; ++kt){
    float4 f0 = {0,0,0,0}, f1 = {0,0,0,0}, f2 = {0,0,0,0}, f3 = {0,0,0,0};
    if (rv){
      const float4* p = (const float4*)(xp + kt*64);
      f0 = p[0]; f1 = p[1]; f2 = p[2]; f3 = p[3];
    }
    uint4 w0 = { pk2(f0.x,f0.y), pk2(f0.z,f0.w), pk2(f1.x,f1.y), pk2(f1.z,f1.w) };
    uint4 w1 = { pk2(f2.x,f2.y), pk2(f2.z,f2.w), pk2(f3.x,f3.y), pk2(f3.z,f3.w) };
    if (kt) __syncthreads();                      // previous tile fully consumed
    *(uint4*)wls       = w0;
    *(uint4*)(wls + 8) = w1;
    __syncthreads();
    bf16x8 b0 = *(const bf16x8*)(bp0 + kt*64);
    bf16x8 b1 = *(const bf16x8*)(bp0 + kt*64 + 32);
    #pragma unroll
    for (int mi = 0; mi < 4; ++mi){
      const unsigned short* ap = Alds + (mi*16 + c0)*72 + g*8;
      bf16x8 a0 = *(const bf16x8*)ap;
      bf16x8 a1 = *(const bf16x8*)(ap + 32);
      acc[mi] = __builtin_amdgcn_mfma_f32_16x16x32_bf16(a0, b0, acc[mi], 0,0,0);
      acc[mi] = __builtin_amdgcn_mfma_f32_16x16x32_bf16(a1, b1, acc[mi], 0,0,0);
    }
  }
  #pragma unroll
  for (int mi = 0; mi < 4; ++mi){
    #pragma unroll
    for (int i = 0; i < 4; ++i){
      int row = rowbase + mi*16 + 4*g + i;        // D: row=(lane>>4)*4+reg, col=lane&15
      if (row < N) h1b[(size_t)row*64 + wv*16 + c0] = f2bf(acc[mi][i]);
    }
  }
}

// ---------------- attn1: per (node,head) dot with att vectors ----------------
__global__ void attn1_kernel(const unsigned short* __restrict__ h1b,
    const float* __restrict__ aw_s, const float* __restrict__ aw_d,
    float* __restrict__ as1, float* __restrict__ ad1, int N)
{
  int t = blockIdx.x*256 + threadIdx.x;
  if (t >= N*8) return;
  int h = t & 7;
  uint4 hv = *(const uint4*)(h1b + (size_t)t*8);  // 8 bf16
  const unsigned* hw = (const unsigned*)&hv;
  const float* ws = aw_s + h*8;
  const float* wd = aw_d + h*8;
  float s = 0.f, d = 0.f;
  #pragma unroll
  for (int j = 0; j < 4; ++j){
    float lo = bf2f((unsigned short)(hw[j] & 0xffff));
    float hi = bf2f((unsigned short)(hw[j] >> 16));
    s = fmaf(lo, ws[2*j], fmaf(hi, ws[2*j+1], s));
    d = fmaf(lo, wd[2*j], fmaf(hi, wd[2*j+1], d));
  }
  as1[t] = s; ad1[t] = d;
}

// ---------------- CSR build ----------------
__global__ void init_deg_kernel(int* __restrict__ deg, int N){
  int t = blockIdx.x*256 + threadIdx.x;
  if (t < N) deg[t] = 1;                          // self-loop pre-counted
}

__global__ void hist_kernel(const int* __restrict__ ei, int* __restrict__ deg, int E){
  int t = blockIdx.x*256 + threadIdx.x;
  if (t < E) atomicAdd(&deg[ei[E + t]], 1);       // row 1 = dst
}

__global__ void scan1_kernel(const int* __restrict__ deg, int* __restrict__ rowstart,
                             int* __restrict__ partial, int N){
  __shared__ int sc[256];
  int t = threadIdx.x;
  int base = blockIdx.x*1024 + t*4;
  int d0=0,d1=0,d2=0,d3=0;
  if (base + 3 < N){
    int4 v = *(const int4*)(deg + base);
    d0=v.x; d1=v.y; d2=v.z; d3=v.w;
  } else {
    if (base   < N) d0 = deg[base];
    if (base+1 < N) d1 = deg[base+1];
    if (base+2 < N) d2 = deg[base+2];
    if (base+3 < N) d3 = deg[base+3];
  }
  int s = d0+d1+d2+d3;
  sc[t] = s; __syncthreads();
  for (int off = 1; off < 256; off <<= 1){
    int v = (t >= off) ? sc[t-off] : 0;
    __syncthreads();
    if (t >= off) sc[t] += v;
    __syncthreads();
  }
  int excl = sc[t] - s;
  if (base   < N) rowstart[base]   = excl;
  if (base+1 < N) rowstart[base+1] = excl + d0;
  if (base+2 < N) rowstart[base+2] = excl + d0 + d1;
  if (base+3 < N) rowstart[base+3] = excl + d0 + d1 + d2;
  if (t == 255) partial[blockIdx.x] = sc[255];
}

__global__ void scan2_kernel(int* __restrict__ partial, int NB){
  __shared__ int sc[128];
  int t = threadIdx.x;
  int v = (t < NB) ? partial[t] : 0;
  sc[t] = v; __syncthreads();
  for (int off = 1; off < 128; off <<= 1){
    int u = (t >= off) ? sc[t-off] : 0;
    __syncthreads();
    if (t >= off) sc[t] += u;
    __syncthreads();
  }
  if (t < NB) partial[t] = sc[t] - v;
  if (t == 127) partial[NB] = sc[127];            // grand total = E + N
}

__global__ void scan3_kernel(int* __restrict__ rowstart, int* __restrict__ cursor,
                             const int* __restrict__ partial, int N, int NB){
  int t = blockIdx.x*256 + threadIdx.x;
  if (t < N){
    int v = rowstart[t] + partial[t >> 10];
    rowstart[t] = v;
    cursor[t]  = v;
  }
  if (t == 0) rowstart[N] = partial[NB];
}

__global__ void scatter_kernel(const int* __restrict__ ei, int* __restrict__ cursor,
                               int* __restrict__ csr, int E, int M){
  int t = blockIdx.x*256 + threadIdx.x;
  if (t >= M) return;
  int s, d;
  if (t < E){ s = ei[t]; d = ei[E + t]; }
  else      { s = d = t - E; }                    // self loops
  int pos = atomicAdd(&cursor[d], 1);
  csr[pos] = s;
}

// ---------------- layer-1 aggregation: wave per dst, 64 features ----------------
__global__ void l1agg_kernel(const int* __restrict__ rowstart, const int* __restrict__ csr,
    const float* __restrict__ as1, const float* __restrict__ ad1,
    const unsigned short* __restrict__ h1b, const float* __restrict__ b1,
    unsigned short* __restrict__ g1b, int N)
{
  int wid = blockIdx.x*4 + (threadIdx.x >> 6);
  if (wid >= N) return;
  int lane = threadIdx.x & 63;
  int h = lane >> 3;
  int r0 = rowstart[wid], r1 = rowstart[wid+1];
  int cnt = r1 - r0;
  int cap = cnt < 64 ? cnt : 64;
  float adv = ad1[wid*8 + h];
  float acc = 0.f, den = 0.f;

  // one coalesced load brings up to 64 edge indices into the wave
  int myidx = csr[r0 + (lane < cap ? lane : cap-1)];

  for (int c = 0; c < cap; c += AGG_UNROLL){
    int   s[AGG_UNROLL];
    float e[AGG_UNROLL], v[AGG_UNROLL];
    #pragma unroll
    for (int j = 0; j < AGG_UNROLL; ++j){
      int cj = (c+j < cap) ? c+j : cap-1;
      s[j] = __shfl(myidx, cj);
    }
    #pragma unroll
    for (int j = 0; j < AGG_UNROLL; ++j) e[j] = as1[s[j]*8 + h];
    #pragma unroll
    for (int j = 0; j < AGG_UNROLL; ++j) v[j] = bf2f(h1b[(size_t)s[j]*64 + lane]);
    #pragma unroll
    for (int j = 0; j < AGG_UNROLL; ++j){
      float t = e[j] + adv;
      t = (t > 0.f) ? t : LR_SLOPE*t;
      float w = __expf(t);
      w = (c+j < cap) ? w : 0.f;
      den += w;
      acc = fmaf(w, v[j], acc);
    }
  }
  for (int r = r0 + 64; r < r1; ++r){             // degree>64: effectively never
    int sx = csr[r];
    float t = as1[sx*8 + h] + adv;
    t = (t > 0.f) ? t : LR_SLOPE*t;
    float w = __expf(t);
    den += w;
    acc = fmaf(w, bf2f(h1b[(size_t)sx*64 + lane]), acc);
  }
  float vv = acc/den + b1[lane];
  vv = (vv > 0.f) ? vv : (__expf(vv) - 1.f);      // ELU fused
  g1b[(size_t)wid*64 + lane] = f2bf(vv);
}

// ---------------- GEMM2: h2[N,40] = g1[N,64] @ W2 (bf16 in, bf16 out) ----------------
__global__ __launch_bounds__(256) void gemm2_kernel(
    const unsigned short* __restrict__ g1b, const unsigned short* __restrict__ wt2,
    unsigned short* __restrict__ h2b, int N)
{
  __shared__ unsigned short Alds[64*72];
  const int tid = threadIdx.x;
  const int wv = tid >> 6, lane = tid & 63;
  const int c0 = lane & 15, g = lane >> 4;
  const int rowbase = blockIdx.x * 64;

  const int sr = tid >> 2, sq = tid & 3;
  const int grow = rowbase + sr;
  const bool rv = grow < N;
  uint4 w0 = {0,0,0,0}, w1 = {0,0,0,0};
  if (rv){
    const unsigned short* gp = g1b + (size_t)grow*64 + sq*16;
    w0 = *(const uint4*)gp;
    w1 = *(const uint4*)(gp + 8);
  }
  unsigned short* wls = Alds + sr*72 + sq*16;
  *(uint4*)wls       = w0;
  *(uint4*)(wls + 8) = w1;
  __syncthreads();

  f32x4 acc[3];
  acc[0] = acc[1] = acc[2] = (f32x4){0.f,0.f,0.f,0.f};
  #pragma unroll
  for (int t2 = 0; t2 < 2; ++t2){
    const unsigned short* ap = Alds + (wv*16 + c0)*72 + t2*32 + g*8;
    bf16x8 a = *(const bf16x8*)ap;
    #pragma unroll
    for (int nf = 0; nf < 3; ++nf){
      bf16x8 b = *(const bf16x8*)(wt2 + (nf*16 + c0)*64 + t2*32 + g*8);
      acc[nf] = __builtin_amdgcn_mfma_f32_16x16x32_bf16(a, b, acc[nf], 0,0,0);
    }
  }
  #pragma unroll
  for (int nf = 0; nf < 3; ++nf){
    int col = nf*16 + c0;
    #pragma unroll
    for (int i = 0; i < 4; ++i){
      int row = rowbase + wv*16 + 4*g + i;
      if (row < N && col < 40) h2b[(size_t)row*40 + col] = f2bf(acc[nf][i]);
    }
  }
}

// ---------------- attn2: 8 lanes per node, 5 features each ----------------
__global__ void attn2_kernel(const unsigned short* __restrict__ h2b,
    const float* __restrict__ aw_s, const float* __restrict__ aw_d,
    float* __restrict__ as2, float* __restrict__ ad2, int N)
{
  int tid = threadIdx.x;
  int wv = blockIdx.x*4 + (tid >> 6);
  int lane = tid & 63;
  int n = wv*8 + (lane >> 3);
  int cq = (lane & 7)*5;
  float s = 0.f, d = 0.f;
  if (n < N){
    const unsigned short* hp = h2b + (size_t)n*40 + cq;
    #pragma unroll
    for (int j = 0; j < 5; ++j){
      float hv = bf2f(hp[j]);
      s += hv * aw_s[cq + j];
      d += hv * aw_d[cq + j];
    }
  }
  s += __shfl_xor(s, 1); s += __shfl_xor(s, 2); s += __shfl_xor(s, 4);
  d += __shfl_xor(d, 1); d += __shfl_xor(d, 2); d += __shfl_xor(d, 4);
  if (n < N && (lane & 7) == 0){ as2[n] = s; ad2[n] = d; }
}

// ---------------- layer-2 aggregation + bias + log_softmax ----------------
__global__ void l2agg_kernel(const int* __restrict__ rowstart, const int* __restrict__ csr,
    const float* __restrict__ as2, const float* __restrict__ ad2,
    const unsigned short* __restrict__ h2b, const float* __restrict__ b2,
    float* __restrict__ out, int N)
{
  int wid = blockIdx.x*4 + (threadIdx.x >> 6);
  if (wid >= N) return;
  int lane = threadIdx.x & 63;
  bool act = lane < 40;
  int r0 = rowstart[wid], r1 = rowstart[wid+1];
  int cnt = r1 - r0;
  int cap = cnt < 64 ? cnt : 64;
  float adv = ad2[wid];
  float acc = 0.f, den = 0.f;

  int myidx = csr[r0 + (lane < cap ? lane : cap-1)];

  for (int c = 0; c < cap; c += AGG_UNROLL){
    int   s[AGG_UNROLL];
    float e[AGG_UNROLL], v[AGG_UNROLL];
    #pragma unroll
    for (int j = 0; j < AGG_UNROLL; ++j){
      int cj = (c+j < cap) ? c+j : cap-1;
      s[j] = __shfl(myidx, cj);
    }
    #pragma unroll
    for (int j = 0; j < AGG_UNROLL; ++j) e[j] = as2[s[j]];
    #pragma unroll
    for (int j = 0; j < AGG_UNROLL; ++j) v[j] = act ? bf2f(h2b[(size_t)s[j]*40 + lane]) : 0.f;
    #pragma unroll
    for (int j = 0; j < AGG_UNROLL; ++j){
      float t = e[j] + adv;
      t = (t > 0.f) ? t : LR_SLOPE*t;
      float w = __expf(t);
      w = (c+j < cap) ? w : 0.f;
      den += w;
      acc = fmaf(w, v[j], acc);
    }
  }
  for (int r = r0 + 64; r < r1; ++r){
    int sx = csr[r];
    float t = as2[sx] + adv;
    t = (t > 0.f) ? t : LR_SLOPE*t;
    float w = __expf(t);
    den += w;
    if (act) acc = fmaf(w, bf2f(h2b[(size_t)sx*40 + lane]), acc);
  }

  float v = act ? (acc/den + b2[lane]) : -1e30f;
  float m = v;
  #pragma unroll
  for (int off = 32; off; off >>= 1) m = fmaxf(m, __shfl_xor(m, off));
  float ex = act ? __expf(v - m) : 0.f;
  float sum = ex;
  #pragma unroll
  for (int off = 32; off; off >>= 1) sum += __shfl_xor(sum, off);
  if (act) out[(size_t)wid*40 + lane] = v - m - __logf(sum);
}

// ---------------- host ----------------
extern "C" void kernel_launch(void* const* d_in, const int* in_sizes, int n_in,
                              void* d_out, int out_size, void* d_ws, size_t ws_size,
                              hipStream_t stream)
{
  const float* x   = (const float*)d_in[0];
  const int*   ei  = (const int*)d_in[1];
  const float* W1  = (const float*)d_in[2];
  const float* aS1 = (const float*)d_in[3];
  const float* aD1 = (const float*)d_in[4];
  const float* b1  = (const float*)d_in[5];
  const float* W2  = (const float*)d_in[6];
  const float* aS2 = (const float*)d_in[7];
  const float* aD2 = (const float*)d_in[8];
  const float* b2  = (const float*)d_in[9];

  const int N  = in_sizes[0] / 512;
  const int E  = in_sizes[1] / 2;
  const int M  = E + N;
  const int NB = (N + 1023) >> 10;

  char* base = (char*)d_ws;
  size_t off = 0;
  auto alloc = [&](size_t bytes)->char* {
    char* p = base + off;
    off += (bytes + 255) & ~(size_t)255;
    return p;
  };
  unsigned short* h1b = (unsigned short*)alloc((size_t)N*64*2);
  unsigned short* g1b = (unsigned short*)alloc((size_t)N*64*2);
  float* as1      = (float*)alloc((size_t)N*8*4);
  float* ad1      = (float*)alloc((size_t)N*8*4);
  int*   deg      = (int*)alloc((size_t)N*4);
  int*   rowstart = (int*)alloc((size_t)(N+1)*4);
  int*   cursor   = (int*)alloc((size_t)N*4);
  int*   csr      = (int*)alloc((size_t)M*4);
  int*   partial  = (int*)alloc(1024);
  unsigned short* wt1 = (unsigned short*)alloc(64*512*2);
  unsigned short* wt2 = (unsigned short*)alloc(48*64*2);
  // safe aliases (h1b/as1/ad1 dead after l1agg)
  unsigned short* h2b = h1b;                      // N*40*2 <= N*64*2
  float* as2 = as1;
  float* ad2 = ad1;
  float* outp = (float*)d_out;

  prep_w1_kernel<<<128, 256, 0, stream>>>(W1, wt1);
  prep_w2_kernel<<<12, 256, 0, stream>>>(W2, wt2);
  gemm1_kernel<<<(N+63)/64, 256, 0, stream>>>(x, wt1, h1b, N);
  attn1_kernel<<<(N*8+255)/256, 256, 0, stream>>>(h1b, aS1, aD1, as1, ad1, N);
  init_deg_kernel<<<(N+255)/256, 256, 0, stream>>>(deg, N);
  hist_kernel<<<(E+255)/256, 256, 0, stream>>>(ei, deg, E);
  scan1_kernel<<<NB, 256, 0, stream>>>(deg, rowstart, partial, N);
  scan2_kernel<<<1, 128, 0, stream>>>(partial, NB);
  scan3_kernel<<<(N+255)/256, 256, 0, stream>>>(rowstart, cursor, partial, N, NB);
  scatter_kernel<<<(M+255)/256, 256, 0, stream>>>(ei, cursor, csr, E, M);
  l1agg_kernel<<<(N+3)/4, 256, 0, stream>>>(rowstart, csr, as1, ad1, h1b, b1, g1b, N);
  gemm2_kernel<<<(N+63)/64, 256, 0, stream>>>(g1b, wt2, h2b, N);
  attn2_kernel<<<(N*8+255)/256, 256, 0, stream>>>(h2b, aS2, aD2, as2, ad2, N);
  l2agg_kernel<<<(N+3)/4, 256, 0, stream>>>(rowstart, csr, as2, ad2, h2b, b2, outp, N);
}

// Round 3
// 360.112 us; speedup vs baseline: 1.8770x; 1.2615x over previous
//
#include <hip/hip_runtime.h>
#include <hip/hip_bf16.h>

typedef __bf16 bf16x8 __attribute__((ext_vector_type(8)));
typedef float f32x4 __attribute__((ext_vector_type(4)));

#define LR_SLOPE 0.2f
#define NBKMAX 256          // buckets of 512 nodes -> supports N <= 131072

static __device__ __forceinline__ unsigned short f2bf(float f){
  union { float f; unsigned u; } v; v.f = f;
  unsigned u = v.u;
  u += 0x7fffu + ((u >> 16) & 1u);   // round-to-nearest-even
  return (unsigned short)(u >> 16);
}
static __device__ __forceinline__ float bf2f(unsigned short us){
  union { unsigned u; float f; } v; v.u = ((unsigned)us) << 16;
  return v.f;
}
static __device__ __forceinline__ unsigned pk2(float a, float b){
  return (unsigned)f2bf(a) | ((unsigned)f2bf(b) << 16);
}

// ---------------- weight prep: transpose + bf16 ----------------
__global__ void prep_w1_kernel(const float* __restrict__ W1, unsigned short* __restrict__ wt1){
  int t = blockIdx.x*256 + threadIdx.x;
  if (t >= 512*64) return;
  int k = t >> 6, n = t & 63;
  wt1[n*512 + k] = f2bf(W1[t]);
}

__global__ void prep_w2_kernel(const float* __restrict__ W2, unsigned short* __restrict__ wt2){
  int t = blockIdx.x*256 + threadIdx.x;
  if (t >= 48*64) return;
  int c = t >> 6, k = t & 63;
  wt2[t] = (c < 40) ? f2bf(W2[k*40 + c]) : (unsigned short)0;
}

// ---------------- GEMM1: h1[N,64] = x[N,512] @ W1 (bf16 MFMA, bf16 out) ----------------
__global__ __launch_bounds__(256) void gemm1_kernel(
    const float* __restrict__ x, const unsigned short* __restrict__ wt1,
    unsigned short* __restrict__ h1b, int N)
{
  __shared__ unsigned short Alds[64*72];
  const int tid = threadIdx.x;
  const int wv = tid >> 6, lane = tid & 63;
  const int c0 = lane & 15, g = lane >> 4;
  const int rowbase = blockIdx.x * 64;

  const int sr = tid >> 2, sq = tid & 3;
  const int grow = rowbase + sr;
  const bool rv = grow < N;
  const float* xp = x + (size_t)grow*512 + sq*16;
  unsigned short* wls = Alds + sr*72 + sq*16;

  f32x4 acc[4];
  acc[0] = acc[1] = acc[2] = acc[3] = (f32x4){0.f,0.f,0.f,0.f};

  const unsigned short* bp0 = wt1 + (size_t)(wv*16 + c0)*512 + g*8;

  for (int kt = 0; kt < 8; ++kt){
    float4 f0 = {0,0,0,0}, f1 = {0,0,0,0}, f2 = {0,0,0,0}, f3 = {0,0,0,0};
    if (rv){
      const float4* p = (const float4*)(xp + kt*64);
      f0 = p[0]; f1 = p[1]; f2 = p[2]; f3 = p[3];
    }
    uint4 w0 = { pk2(f0.x,f0.y), pk2(f0.z,f0.w), pk2(f1.x,f1.y), pk2(f1.z,f1.w) };
    uint4 w1 = { pk2(f2.x,f2.y), pk2(f2.z,f2.w), pk2(f3.x,f3.y), pk2(f3.z,f3.w) };
    if (kt) __syncthreads();
    *(uint4*)wls       = w0;
    *(uint4*)(wls + 8) = w1;
    __syncthreads();
    bf16x8 b0 = *(const bf16x8*)(bp0 + kt*64);
    bf16x8 b1 = *(const bf16x8*)(bp0 + kt*64 + 32);
    #pragma unroll
    for (int mi = 0; mi < 4; ++mi){
      const unsigned short* ap = Alds + (mi*16 + c0)*72 + g*8;
      bf16x8 a0 = *(const bf16x8*)ap;
      bf16x8 a1 = *(const bf16x8*)(ap + 32);
      acc[mi] = __builtin_amdgcn_mfma_f32_16x16x32_bf16(a0, b0, acc[mi], 0,0,0);
      acc[mi] = __builtin_amdgcn_mfma_f32_16x16x32_bf16(a1, b1, acc[mi], 0,0,0);
    }
  }
  #pragma unroll
  for (int mi = 0; mi < 4; ++mi){
    #pragma unroll
    for (int i = 0; i < 4; ++i){
      int row = rowbase + mi*16 + 4*g + i;
      if (row < N) h1b[(size_t)row*64 + wv*16 + c0] = f2bf(acc[mi][i]);
    }
  }
}

// ---------------- attn1 ----------------
__global__ void attn1_kernel(const unsigned short* __restrict__ h1b,
    const float* __restrict__ aw_s, const float* __restrict__ aw_d,
    float* __restrict__ as1, float* __restrict__ ad1, int N)
{
  int t = blockIdx.x*256 + threadIdx.x;
  if (t >= N*8) return;
  int h = t & 7;
  uint4 hv = *(const uint4*)(h1b + (size_t)t*8);
  const unsigned* hw = (const unsigned*)&hv;
  const float* ws = aw_s + h*8;
  const float* wd = aw_d + h*8;
  float s = 0.f, d = 0.f;
  #pragma unroll
  for (int j = 0; j < 4; ++j){
    float lo = bf2f((unsigned short)(hw[j] & 0xffff));
    float hi = bf2f((unsigned short)(hw[j] >> 16));
    s = fmaf(lo, ws[2*j], fmaf(hi, ws[2*j+1], s));
    d = fmaf(lo, wd[2*j], fmaf(hi, wd[2*j+1], d));
  }
  as1[t] = s; ad1[t] = d;
}

// ---------------- CSR build: histogram + scan ----------------
__global__ void init_deg_kernel(int* __restrict__ deg, int N){
  int t = blockIdx.x*256 + threadIdx.x;
  if (t < N) deg[t] = 1;
}

__global__ void hist_kernel(const int* __restrict__ ei, int* __restrict__ deg, int E){
  int t = blockIdx.x*256 + threadIdx.x;
  if (t < E) atomicAdd(&deg[ei[E + t]], 1);
}

__global__ void scan1_kernel(const int* __restrict__ deg, int* __restrict__ rowstart,
                             int* __restrict__ partial, int N){
  __shared__ int sc[256];
  int t = threadIdx.x;
  int base = blockIdx.x*1024 + t*4;
  int d0=0,d1=0,d2=0,d3=0;
  if (base + 3 < N){
    int4 v = *(const int4*)(deg + base);
    d0=v.x; d1=v.y; d2=v.z; d3=v.w;
  } else {
    if (base   < N) d0 = deg[base];
    if (base+1 < N) d1 = deg[base+1];
    if (base+2 < N) d2 = deg[base+2];
    if (base+3 < N) d3 = deg[base+3];
  }
  int s = d0+d1+d2+d3;
  sc[t] = s; __syncthreads();
  for (int off = 1; off < 256; off <<= 1){
    int v = (t >= off) ? sc[t-off] : 0;
    __syncthreads();
    if (t >= off) sc[t] += v;
    __syncthreads();
  }
  int excl = sc[t] - s;
  if (base   < N) rowstart[base]   = excl;
  if (base+1 < N) rowstart[base+1] = excl + d0;
  if (base+2 < N) rowstart[base+2] = excl + d0 + d1;
  if (base+3 < N) rowstart[base+3] = excl + d0 + d1 + d2;
  if (t == 255) partial[blockIdx.x] = sc[255];
}

__global__ void scan2_kernel(int* __restrict__ partial, int NB){
  __shared__ int sc[128];
  int t = threadIdx.x;
  int v = (t < NB) ? partial[t] : 0;
  sc[t] = v; __syncthreads();
  for (int off = 1; off < 128; off <<= 1){
    int u = (t >= off) ? sc[t-off] : 0;
    __syncthreads();
    if (t >= off) sc[t] += u;
    __syncthreads();
  }
  if (t < NB) partial[t] = sc[t] - v;
  if (t == 127) partial[NB] = sc[127];
}

__global__ void scan3_kernel(int* __restrict__ rowstart,
                             const int* __restrict__ partial, int N, int NB){
  int t = blockIdx.x*256 + threadIdx.x;
  if (t < N) rowstart[t] = rowstart[t] + partial[t >> 10];
  if (t == 0) rowstart[N] = partial[NB];
}

__global__ void init_bcur_kernel(const int* __restrict__ rowstart, int* __restrict__ bcur, int NBK){
  int t = threadIdx.x;
  if (t < NBK) bcur[t] = rowstart[t << 9];
}

// ---------------- bucket phase A: coarse sort into 512-node buckets ----------------
// entry = (src<<9) | (dst & 511); bucket = dst>>9. Each (block,bucket) claims a
// contiguous run in the bucket's final CSR region -> write-combining friendly.
__global__ __launch_bounds__(256) void bucketA_kernel(
    const int* __restrict__ ei, int* __restrict__ bcur,
    unsigned* __restrict__ bucketed, int E, int M, int NBK)
{
  __shared__ int hist[NBKMAX];
  __shared__ int gb[NBKMAX];
  const int tid = threadIdx.x;
  const int t0 = blockIdx.x * 2048;
  for (int i = tid; i < NBK; i += 256) hist[i] = 0;
  __syncthreads();

  unsigned pe[8]; int bk[8], rnk[8];
  #pragma unroll
  for (int j = 0; j < 8; ++j){
    int m = t0 + j*256 + tid;
    if (m < M){
      int s, d;
      if (m < E){ s = ei[m]; d = ei[E + m]; }
      else      { s = d = m - E; }
      bk[j] = d >> 9;
      pe[j] = ((unsigned)s << 9) | (unsigned)(d & 511);
      rnk[j] = atomicAdd(&hist[bk[j]], 1);
    } else bk[j] = -1;
  }
  __syncthreads();
  for (int i = tid; i < NBK; i += 256) gb[i] = atomicAdd(&bcur[i], hist[i]);
  __syncthreads();
  #pragma unroll
  for (int j = 0; j < 8; ++j){
    if (bk[j] >= 0) bucketed[gb[bk[j]] + rnk[j]] = pe[j];
  }
}

// ---------------- bucket phase B: fine scatter within exclusive L2 region ----------------
__global__ __launch_bounds__(512) void bucketB_kernel(
    const unsigned* __restrict__ bucketed, const int* __restrict__ rowstart,
    int* __restrict__ csr, int N)
{
  __shared__ int cur[512];
  const int k = blockIdx.x;
  const int nodebase = k << 9;
  const int nn = min(512, N - nodebase);
  for (int i = threadIdx.x; i < nn; i += 512) cur[i] = rowstart[nodebase + i];
  __syncthreads();
  const int lo = rowstart[nodebase];
  const int hi = rowstart[nodebase + nn];
  for (int m = lo + threadIdx.x; m < hi; m += 512){
    unsigned e = bucketed[m];
    int pos = atomicAdd(&cur[e & 511], 1);
    csr[pos] = (int)(e >> 9);
  }
}

// ---------------- layer-1 aggregation (wave per dst, wave-wide weights) ----------------
__global__ void l1agg_kernel(const int* __restrict__ rowstart, const int* __restrict__ csr,
    const float* __restrict__ as1, const float* __restrict__ ad1,
    const unsigned short* __restrict__ h1b, const float* __restrict__ b1,
    unsigned short* __restrict__ g1b, int N)
{
  int wid = blockIdx.x*4 + (threadIdx.x >> 6);
  if (wid >= N) return;
  const int lane = threadIdx.x & 63;
  const int hf = lane >> 3;          // head for the slot (feature) role
  const int jq = lane >> 3;          // edge-in-chunk for the weight role
  const int hq = lane & 7;           // head for the weight role
  int r0 = rowstart[wid], r1 = rowstart[wid+1];
  int cnt = r1 - r0;
  int cap = cnt < 64 ? cnt : 64;
  float advv = ad1[wid*8 + hq];
  float acc = 0.f, den = 0.f;

  int myidx = csr[r0 + (lane < cap ? lane : cap-1)];

  // prefetch first chunk's as1 values (8 edges x 8 heads across the wave)
  int sw = __shfl(myidx, jq < cap ? jq : cap-1);
  float ev = as1[sw*8 + hq];

  for (int c = 0; c < cap; c += 8){
    float evn = 0.f;
    if (c + 8 < cap){
      int cj = c + 8 + jq;
      int swn = __shfl(myidx, cj < cap ? cj : cap-1);
      evn = as1[swn*8 + hq];
    }
    float t = ev + advv;
    t = (t > 0.f) ? t : LR_SLOPE*t;
    float w = __expf(t);
    if (c + jq >= cap) w = 0.f;
    #pragma unroll
    for (int j = 0; j < 8; ++j){
      float wj = __shfl(w, j*8 + hf);
      den += wj;
      int sj = __shfl(myidx, c + j);
      acc = fmaf(wj, bf2f(h1b[sj*64 + lane]), acc);
    }
    ev = evn;
  }
  for (int r = r0 + 64; r < r1; ++r){             // degree>64 fallback
    int sx = csr[r];
    float t = as1[sx*8 + hf] + ad1[wid*8 + hf];
    t = (t > 0.f) ? t : LR_SLOPE*t;
    float w = __expf(t);
    den += w;
    acc = fmaf(w, bf2f(h1b[sx*64 + lane]), acc);
  }
  float vv = acc/den + b1[lane];
  vv = (vv > 0.f) ? vv : (__expf(vv) - 1.f);      // ELU fused
  g1b[(size_t)wid*64 + lane] = f2bf(vv);
}

// ---------------- GEMM2 ----------------
__global__ __launch_bounds__(256) void gemm2_kernel(
    const unsigned short* __restrict__ g1b, const unsigned short* __restrict__ wt2,
    unsigned short* __restrict__ h2b, int N)
{
  __shared__ unsigned short Alds[64*72];
  const int tid = threadIdx.x;
  const int wv = tid >> 6, lane = tid & 63;
  const int c0 = lane & 15, g = lane >> 4;
  const int rowbase = blockIdx.x * 64;

  const int sr = tid >> 2, sq = tid & 3;
  const int grow = rowbase + sr;
  const bool rv = grow < N;
  uint4 w0 = {0,0,0,0}, w1 = {0,0,0,0};
  if (rv){
    const unsigned short* gp = g1b + (size_t)grow*64 + sq*16;
    w0 = *(const uint4*)gp;
    w1 = *(const uint4*)(gp + 8);
  }
  unsigned short* wls = Alds + sr*72 + sq*16;
  *(uint4*)wls       = w0;
  *(uint4*)(wls + 8) = w1;
  __syncthreads();

  f32x4 acc[3];
  acc[0] = acc[1] = acc[2] = (f32x4){0.f,0.f,0.f,0.f};
  #pragma unroll
  for (int t2 = 0; t2 < 2; ++t2){
    const unsigned short* ap = Alds + (wv*16 + c0)*72 + t2*32 + g*8;
    bf16x8 a = *(const bf16x8*)ap;
    #pragma unroll
    for (int nf = 0; nf < 3; ++nf){
      bf16x8 b = *(const bf16x8*)(wt2 + (nf*16 + c0)*64 + t2*32 + g*8);
      acc[nf] = __builtin_amdgcn_mfma_f32_16x16x32_bf16(a, b, acc[nf], 0,0,0);
    }
  }
  #pragma unroll
  for (int nf = 0; nf < 3; ++nf){
    int col = nf*16 + c0;
    #pragma unroll
    for (int i = 0; i < 4; ++i){
      int row = rowbase + wv*16 + 4*g + i;
      if (row < N && col < 40) h2b[(size_t)row*40 + col] = f2bf(acc[nf][i]);
    }
  }
}

// ---------------- attn2 ----------------
__global__ void attn2_kernel(const unsigned short* __restrict__ h2b,
    const float* __restrict__ aw_s, const float* __restrict__ aw_d,
    float* __restrict__ as2, float* __restrict__ ad2, int N)
{
  int tid = threadIdx.x;
  int wv = blockIdx.x*4 + (tid >> 6);
  int lane = tid & 63;
  int n = wv*8 + (lane >> 3);
  int cq = (lane & 7)*5;
  float s = 0.f, d = 0.f;
  if (n < N){
    const unsigned short* hp = h2b + (size_t)n*40 + cq;
    #pragma unroll
    for (int j = 0; j < 5; ++j){
      float hv = bf2f(hp[j]);
      s += hv * aw_s[cq + j];
      d += hv * aw_d[cq + j];
    }
  }
  s += __shfl_xor(s, 1); s += __shfl_xor(s, 2); s += __shfl_xor(s, 4);
  d += __shfl_xor(d, 1); d += __shfl_xor(d, 2); d += __shfl_xor(d, 4);
  if (n < N && (lane & 7) == 0){ as2[n] = s; ad2[n] = d; }
}

// ---------------- layer-2 aggregation + bias + log_softmax ----------------
__global__ void l2agg_kernel(const int* __restrict__ rowstart, const int* __restrict__ csr,
    const float* __restrict__ as2, const float* __restrict__ ad2,
    const unsigned short* __restrict__ h2b, const float* __restrict__ b2,
    float* __restrict__ out, int N)
{
  int wid = blockIdx.x*4 + (threadIdx.x >> 6);
  if (wid >= N) return;
  const int lane = threadIdx.x & 63;
  const bool act = lane < 40;
  int r0 = rowstart[wid], r1 = rowstart[wid+1];
  int cnt = r1 - r0;
  int cap = cnt < 64 ? cnt : 64;
  float adv = ad2[wid];

  int myidx = csr[r0 + (lane < cap ? lane : cap-1)];

  // all <=64 edge weights in one shot
  float t = as2[myidx] + adv;
  t = (t > 0.f) ? t : LR_SLOPE*t;
  float w = __expf(t);
  if (lane >= cap) w = 0.f;
  float den = w;
  #pragma unroll
  for (int off = 32; off; off >>= 1) den += __shfl_xor(den, off);

  float acc = 0.f;
  for (int c = 0; c < cap; c += 8){
    #pragma unroll
    for (int j = 0; j < 8; ++j){
      float wj = __shfl(w, c + j);
      int   sj = __shfl(myidx, c + j);
      float vj = act ? bf2f(h2b[sj*40 + lane]) : 0.f;
      acc = fmaf(wj, vj, acc);
    }
  }
  for (int r = r0 + 64; r < r1; ++r){             // degree>64 fallback
    int sx = csr[r];
    float tt = as2[sx] + adv;
    tt = (tt > 0.f) ? tt : LR_SLOPE*tt;
    float ww = __expf(tt);
    den += ww;
    if (act) acc = fmaf(ww, bf2f(h2b[sx*40 + lane]), acc);
  }

  float v = act ? (acc/den + b2[lane]) : -1e30f;
  float m = v;
  #pragma unroll
  for (int off = 32; off; off >>= 1) m = fmaxf(m, __shfl_xor(m, off));
  float ex = act ? __expf(v - m) : 0.f;
  float sum = ex;
  #pragma unroll
  for (int off = 32; off; off >>= 1) sum += __shfl_xor(sum, off);
  if (act) out[(size_t)wid*40 + lane] = v - m - __logf(sum);
}

// ---------------- host ----------------
extern "C" void kernel_launch(void* const* d_in, const int* in_sizes, int n_in,
                              void* d_out, int out_size, void* d_ws, size_t ws_size,
                              hipStream_t stream)
{
  const float* x   = (const float*)d_in[0];
  const int*   ei  = (const int*)d_in[1];
  const float* W1  = (const float*)d_in[2];
  const float* aS1 = (const float*)d_in[3];
  const float* aD1 = (const float*)d_in[4];
  const float* b1  = (const float*)d_in[5];
  const float* W2  = (const float*)d_in[6];
  const float* aS2 = (const float*)d_in[7];
  const float* aD2 = (const float*)d_in[8];
  const float* b2  = (const float*)d_in[9];

  const int N   = in_sizes[0] / 512;
  const int E   = in_sizes[1] / 2;
  const int M   = E + N;
  const int NB  = (N + 1023) >> 10;
  const int NBK = (N + 511) >> 9;      // 512-node buckets (<= NBKMAX)

  char* base = (char*)d_ws;
  size_t off = 0;
  auto alloc = [&](size_t bytes)->char* {
    char* p = base + off;
    off += (bytes + 255) & ~(size_t)255;
    return p;
  };
  unsigned short* h1b = (unsigned short*)alloc((size_t)N*64*2);
  unsigned short* g1b = (unsigned short*)alloc((size_t)N*64*2);
  float* as1      = (float*)alloc((size_t)N*8*4);
  float* ad1      = (float*)alloc((size_t)N*8*4);
  int*   deg      = (int*)alloc((size_t)N*4);
  int*   rowstart = (int*)alloc((size_t)(N+1)*4);
  int*   bcur     = (int*)alloc((size_t)NBKMAX*4);
  int*   csr      = (int*)alloc((size_t)M*4);
  int*   partial  = (int*)alloc(1024);
  unsigned short* wt1 = (unsigned short*)alloc(64*512*2);
  unsigned short* wt2 = (unsigned short*)alloc(48*64*2);
  // aliases: bucketed (M*4 <= N*128) lives in g1b's buffer (dead until l1agg);
  // h2b/as2/ad2 reuse layer-1 buffers (dead after l1agg).
  unsigned* bucketed = (unsigned*)g1b;
  unsigned short* h2b = h1b;
  float* as2 = as1;
  float* ad2 = ad1;
  float* outp = (float*)d_out;

  prep_w1_kernel<<<128, 256, 0, stream>>>(W1, wt1);
  prep_w2_kernel<<<12, 256, 0, stream>>>(W2, wt2);
  gemm1_kernel<<<(N+63)/64, 256, 0, stream>>>(x, wt1, h1b, N);
  attn1_kernel<<<(N*8+255)/256, 256, 0, stream>>>(h1b, aS1, aD1, as1, ad1, N);
  init_deg_kernel<<<(N+255)/256, 256, 0, stream>>>(deg, N);
  hist_kernel<<<(E+255)/256, 256, 0, stream>>>(ei, deg, E);
  scan1_kernel<<<NB, 256, 0, stream>>>(deg, rowstart, partial, N);
  scan2_kernel<<<1, 128, 0, stream>>>(partial, NB);
  scan3_kernel<<<(N+255)/256, 256, 0, stream>>>(rowstart, partial, N, NB);
  init_bcur_kernel<<<1, 256, 0, stream>>>(rowstart, bcur, NBK);
  bucketA_kernel<<<(M+2047)/2048, 256, 0, stream>>>(ei, bcur, bucketed, E, M, NBK);
  bucketB_kernel<<<NBK, 512, 0, stream>>>(bucketed, rowstart, csr, N);
  l1agg_kernel<<<(N+3)/4, 256, 0, stream>>>(rowstart, csr, as1, ad1, h1b, b1, g1b, N);
  gemm2_kernel<<<(N+63)/64, 256, 0, stream>>>(g1b, wt2, h2b, N);
  attn2_kernel<<<(N*8+255)/256, 256, 0, stream>>>(h2b, aS2, aD2, as2, ad2, N);
  l2agg_kernel<<<(N+3)/4, 256, 0, stream>>>(rowstart, csr, as2, ad2, h2b, b2, outp, N);
}